// Round 1
// 238.013 us; speedup vs baseline: 1.0649x; 1.0649x over previous
//
#include <hip/hip_runtime.h>
#include <hip/hip_bf16.h>

constexpr int B_  = 128;
constexpr int N_  = 512;
constexpr int F_  = 64;
constexpr int D_  = 128;
constexpr int E_  = 8192;
constexpr int BN_ = B_ * N_;              // 65536
constexpr float SLOPE = 0.2f;
constexpr float EPS_  = 1e-5f;
constexpr int OFF_PRED = BN_ * F_;        // 4194304 (elements)
constexpr int OFF_W    = OFF_PRED + BN_;  // 4259840

// workspace float-offsets
constexpr int WS_ALPHA  = 0;       // f[8192]
constexpr int WS_COEF   = 8192;    // f[8192]
constexpr int WS_ASELF  = 16384;   // f[512]
constexpr int WS_STATS  = 16896;   // f[256]  (sum | sumsq)
constexpr int WS_SRCS   = 17152;   // i[8192]
constexpr int WS_RS     = 25344;   // i[513]
constexpr int WS_WLT    = 25860;   // u16[128n][64k]   (bf16 Wl^T)
constexpr int WS_WRT    = 29956;   // u16[64n][128k]   (bf16 Wr^T)
constexpr int WS_Y      = 34052;   // bf16[BN*64]  (byte 136208, 16B aligned)

// scratch carved out of `out` (fully overwritten later by kD_final's recons):
//   XT bf16 [B][64 f][512 m]  at u16 offset 0         (4,194,304 u16 = 8.4 MB)
//   A  bf16 [512 n][512 m]    at u16 offset 4,194,304 (262,144 u16 = 0.5 MB)
// both end well below OFF_PRED floats (byte 16,777,216).
constexpr int A_U16 = 4194304;

typedef __attribute__((ext_vector_type(8))) short bf16x8;
typedef __attribute__((ext_vector_type(4))) float f32x4;

__device__ __forceinline__ unsigned f2ord(float f) {
  unsigned u = __float_as_uint(f);
  return (u & 0x80000000u) ? ~u : (u | 0x80000000u);
}
__device__ __forceinline__ float ord2f(unsigned u) {
  return (u & 0x80000000u) ? __uint_as_float(u & 0x7fffffffu) : __uint_as_float(~u);
}
__device__ __forceinline__ float lrelu(float w) { return w > 0.f ? w : SLOPE * w; }
__device__ __forceinline__ unsigned short f2b(float v) {
  __hip_bfloat16 h = __float2bfloat16(v);
  return *(unsigned short*)&h;
}
__device__ __forceinline__ float b2f(unsigned short u) {
  __hip_bfloat16 h = *(__hip_bfloat16*)&u;
  return __bfloat162float(h);
}

// K0: X transpose to bf16 XT[b][f][m] (scratch in out) + zero dense A.
// 256 blocks x 256 thr. Uncoalesced float4 reads (L1/L2-absorbed, full-line
// consumption across the 16 unrolled loads), coalesced u16 row writes.
__global__ __launch_bounds__(256) void k_xt(
    const float* __restrict__ X, unsigned short* __restrict__ outs)
{
  const int t = threadIdx.x;
  // zero A: 256 blk * 256 thr * 8 B = 512 KB
  ((unsigned long long*)(outs + A_U16))[blockIdx.x * 256 + t] = 0ull;
  const int b = blockIdx.x >> 1;
  const int m = ((blockIdx.x & 1) << 8) + t;
  const float* xrow = X + ((size_t)b * N_ + m) * F_;
  unsigned short* xtb = outs + (size_t)b * (F_ * N_);
  #pragma unroll
  for (int f4 = 0; f4 < 16; f4++) {
    float4 v = *(const float4*)(xrow + f4 * 4);
    xtb[(f4 * 4 + 0) * N_ + m] = f2b(v.x);
    xtb[(f4 * 4 + 1) * N_ + m] = f2b(v.y);
    xtb[(f4 * 4 + 2) * N_ + m] = f2b(v.z);
    xtb[(f4 * 4 + 3) * N_ + m] = f2b(v.w);
  }
}

// K1: attention softmax + dense bf16 A build + bf16 transposed weight prep. 1 block.
__global__ __launch_bounds__(512) void k_attn(
    const float* __restrict__ W, const int* __restrict__ ei,
    const float* __restrict__ Wl, const float* __restrict__ Wr,
    float* ws, unsigned short* __restrict__ Abf)
{
  __shared__ unsigned amax[N_];
  __shared__ float denom[N_];
  __shared__ int deg[N_];
  __shared__ int fpos[N_];
  __shared__ int rs[N_ + 1];
  float* f = (float*)ws;
  int* srcs = (int*)ws + WS_SRCS;
  unsigned short* wlT = (unsigned short*)(ws + WS_WLT);
  unsigned short* wrT = (unsigned short*)(ws + WS_WRT);
  const int t = threadIdx.x;
  {
    float al = lrelu(W[t * N_ + t]);          // self-loop
    f[WS_ASELF + t] = al;
    amax[t] = f2ord(al);
    denom[t] = 0.f;
    deg[t] = 0;
    fpos[t] = 0;
  }
  if (t < 256) f[WS_STATS + t] = 0.f;
  // bf16 transposed weights for MFMA B-fragments
  for (int i = t; i < F_ * D_; i += 512) {    // WlT[n][k] = Wl[k][n]
    int n = i >> 6, k = i & 63;
    wlT[i] = f2b(Wl[k * D_ + n]);
  }
  for (int i = t; i < D_ * F_; i += 512) {    // WrT[n][k] = Wr[k][n]
    int n = i >> 7, k = i & 127;
    wrT[i] = f2b(Wr[k * F_ + n]);
  }
  __syncthreads();
  for (int e = t; e < E_; e += 512) {
    int s = ei[e], d = ei[E_ + e];
    float al = lrelu(W[d * N_ + s]);
    f[WS_ALPHA + e] = al;
    atomicMax(&amax[d], f2ord(al));
    atomicAdd(&deg[d], 1);
  }
  __syncthreads();
  if (t == 0) {
    int acc = 0;
    for (int n = 0; n < N_; n++) { rs[n] = acc; acc += deg[n]; }
    rs[N_] = acc;
  }
  __syncthreads();
  {
    float ez = __expf(f[WS_ASELF + t] - ord2f(amax[t]));
    f[WS_ASELF + t] = ez;
    atomicAdd(&denom[t], ez);
  }
  for (int e = t; e < E_; e += 512) {
    int s = ei[e], d = ei[E_ + e];
    float ez = __expf(f[WS_ALPHA + e] - ord2f(amax[d]));
    atomicAdd(&denom[d], ez);
    int pos = rs[d] + atomicAdd(&fpos[d], 1);
    f[WS_COEF + pos] = ez;
    srcs[pos] = s;
  }
  __syncthreads();
  {
    // build dense row t of A (bf16). Row was zeroed by k_xt; only thread t
    // touches row t, so duplicate edges accumulate safely (+=).
    float inv = 1.f / denom[t];
    unsigned short* arow = Abf + t * N_;
    arow[t] = f2b(f[WS_ASELF + t] * inv);     // self-loop (src != dst always)
    for (int j = rs[t]; j < rs[t + 1]; j++) {
      float c = f[WS_COEF + j] * inv;
      int s = srcs[j];
      arow[s] = f2b(b2f(arow[s]) + c);
    }
  }
}

// K2: aggregation as dense MFMA GEMM.  Y^T_b = XT_b(64x512) @ A^T  =>
// Y[r][f] bf16 in ws (same layout kC/kD consume).  Both fragment streams are
// contiguous global reads (XT rows / A rows), no LDS, no barriers.
// grid = 128 b x 8 n-slices; 4 waves; wave wv = f-tile, 4 n-tiles each.
__global__ __launch_bounds__(256) void kB_gemm(
    const unsigned short* __restrict__ XT, float* ws)
{
  unsigned short* Yb = (unsigned short*)((float*)ws + WS_Y);
  const unsigned short* Abf = XT + A_U16;
  const int t = threadIdx.x;
  const int wv = t >> 6, lane = t & 63;
  const int m = lane & 15, quad = lane >> 4;
  const int b = blockIdx.x >> 3, ns = blockIdx.x & 7;
  const int n0 = ns * 64;
  const unsigned short* af = XT + (size_t)b * (F_ * N_) + (wv * 16 + m) * N_;
  f32x4 acc[4] = {{0.f,0.f,0.f,0.f},{0.f,0.f,0.f,0.f},
                  {0.f,0.f,0.f,0.f},{0.f,0.f,0.f,0.f}};
  #pragma unroll 4
  for (int kk = 0; kk < 16; kk++) {
    const int k0 = kk * 32 + quad * 8;
    bf16x8 a = *(const bf16x8*)(af + k0);
    #pragma unroll
    for (int nt = 0; nt < 4; nt++) {
      bf16x8 bb = *(const bf16x8*)(Abf + (n0 + nt * 16 + m) * N_ + k0);
      acc[nt] = __builtin_amdgcn_mfma_f32_16x16x32_bf16(a, bb, acc[nt], 0, 0, 0);
    }
  }
  // D-layout: col(lane&15) = n within tile, row(quad*4+i) = f  ->  pack 4
  // consecutive f as ushort4 per lane, store into Y[r][f].
  const size_t rb = (size_t)b * N_ + n0 + m;
  #pragma unroll
  for (int nt = 0; nt < 4; nt++) {
    ushort4 y4;
    y4.x = f2b(acc[nt][0]); y4.y = f2b(acc[nt][1]);
    y4.z = f2b(acc[nt][2]); y4.w = f2b(acc[nt][3]);
    *(ushort4*)(Yb + (rb + nt * 16) * F_ + wv * 16 + quad * 4) = y4;
  }
}

// K3: BN stats via MFMA (h = Y @ Wl on 16x16x32 bf16 matrix cores).
// 256 blocks x 256 rows; per-lane sum/sumsq, quad-shuffle reduce, atomics.
__global__ __launch_bounds__(256) void kC_stats(float* ws)
{
  float* f = (float*)ws;
  const unsigned short* Yb  = (const unsigned short*)(f + WS_Y);
  const unsigned short* wlT = (const unsigned short*)(f + WS_WLT);
  const int t = threadIdx.x;
  const int wv = t >> 6, lane = t & 63;
  const int m = lane & 15, quad = lane >> 4;
  const int T0 = 2 * wv, T1 = 2 * wv + 1;   // column tiles (of 8)
  // B-fragments are row-invariant: load once
  bf16x8 b00 = *(const bf16x8*)(wlT + (T0 * 16 + m) * 64 +  0 + quad * 8);
  bf16x8 b01 = *(const bf16x8*)(wlT + (T0 * 16 + m) * 64 + 32 + quad * 8);
  bf16x8 b10 = *(const bf16x8*)(wlT + (T1 * 16 + m) * 64 +  0 + quad * 8);
  bf16x8 b11 = *(const bf16x8*)(wlT + (T1 * 16 + m) * 64 + 32 + quad * 8);
  float sum0 = 0.f, sq0 = 0.f, sum1 = 0.f, sq1 = 0.f;
  const int rowblk = blockIdx.x * 256;
  for (int st = 0; st < 16; st++) {
    const int rowbase = rowblk + st * 16;
    bf16x8 a0 = *(const bf16x8*)(Yb + (size_t)(rowbase + m) * 64 +  0 + quad * 8);
    bf16x8 a1 = *(const bf16x8*)(Yb + (size_t)(rowbase + m) * 64 + 32 + quad * 8);
    f32x4 acc0 = {0.f, 0.f, 0.f, 0.f}, acc1 = {0.f, 0.f, 0.f, 0.f};
    acc0 = __builtin_amdgcn_mfma_f32_16x16x32_bf16(a0, b00, acc0, 0, 0, 0);
    acc0 = __builtin_amdgcn_mfma_f32_16x16x32_bf16(a1, b01, acc0, 0, 0, 0);
    acc1 = __builtin_amdgcn_mfma_f32_16x16x32_bf16(a0, b10, acc1, 0, 0, 0);
    acc1 = __builtin_amdgcn_mfma_f32_16x16x32_bf16(a1, b11, acc1, 0, 0, 0);
    #pragma unroll
    for (int i = 0; i < 4; i++) {
      sum0 += acc0[i]; sq0 += acc0[i] * acc0[i];
      sum1 += acc1[i]; sq1 += acc1[i] * acc1[i];
    }
  }
  // reduce across quads (rows) -> per-column totals in lanes 0..15
  sum0 += __shfl_xor(sum0, 16); sum0 += __shfl_xor(sum0, 32);
  sq0  += __shfl_xor(sq0, 16);  sq0  += __shfl_xor(sq0, 32);
  sum1 += __shfl_xor(sum1, 16); sum1 += __shfl_xor(sum1, 32);
  sq1  += __shfl_xor(sq1, 16);  sq1  += __shfl_xor(sq1, 32);
  if (quad == 0) {
    atomicAdd(&f[WS_STATS + T0 * 16 + m], sum0);
    atomicAdd(&f[WS_STATS + 128 + T0 * 16 + m], sq0);
    atomicAdd(&f[WS_STATS + T1 * 16 + m], sum1);
    atomicAdd(&f[WS_STATS + 128 + T1 * 16 + m], sq1);
  }
}

// K4: MFMA epilogue: h = Y@Wl -> BN+ReLU -> z (LDS bf16) -> z@Wr + both heads.
__global__ __launch_bounds__(256) void kD_final(
    const float* __restrict__ gamma, const float* __restrict__ beta,
    const float* __restrict__ br, const float* __restrict__ wp,
    const float* __restrict__ bp, float* ws, float* __restrict__ out)
{
  __shared__ unsigned short zs[16 * D_];   // 4 KB bf16 z-tile
  float* f = (float*)ws;
  const unsigned short* Yb  = (const unsigned short*)(f + WS_Y);
  const unsigned short* wlT = (const unsigned short*)(f + WS_WLT);
  const unsigned short* wrT = (const unsigned short*)(f + WS_WRT);
  const int t = threadIdx.x;
  const int wv = t >> 6, lane = t & 63;
  const int m = lane & 15, quad = lane >> 4;
  const size_t row0 = (size_t)blockIdx.x * 16;

  // ---- GEMM1: h tile [16 x 128], wave wv covers col-tiles 2wv, 2wv+1 ----
  const int T0 = 2 * wv, T1 = 2 * wv + 1;
  bf16x8 a0 = *(const bf16x8*)(Yb + (row0 + m) * 64 +  0 + quad * 8);
  bf16x8 a1 = *(const bf16x8*)(Yb + (row0 + m) * 64 + 32 + quad * 8);
  bf16x8 b00 = *(const bf16x8*)(wlT + (T0 * 16 + m) * 64 +  0 + quad * 8);
  bf16x8 b01 = *(const bf16x8*)(wlT + (T0 * 16 + m) * 64 + 32 + quad * 8);
  bf16x8 b10 = *(const bf16x8*)(wlT + (T1 * 16 + m) * 64 +  0 + quad * 8);
  bf16x8 b11 = *(const bf16x8*)(wlT + (T1 * 16 + m) * 64 + 32 + quad * 8);
  f32x4 acc0 = {0.f, 0.f, 0.f, 0.f}, acc1 = {0.f, 0.f, 0.f, 0.f};
  acc0 = __builtin_amdgcn_mfma_f32_16x16x32_bf16(a0, b00, acc0, 0, 0, 0);
  acc0 = __builtin_amdgcn_mfma_f32_16x16x32_bf16(a1, b01, acc0, 0, 0, 0);
  acc1 = __builtin_amdgcn_mfma_f32_16x16x32_bf16(a0, b10, acc1, 0, 0, 0);
  acc1 = __builtin_amdgcn_mfma_f32_16x16x32_bf16(a1, b11, acc1, 0, 0, 0);

  // ---- BN + ReLU -> z (bf16 in LDS) ----
  {
    int c0 = T0 * 16 + m, c1 = T1 * 16 + m;
    float mu0 = f[WS_STATS + c0] * (1.f / (float)BN_);
    float v0  = f[WS_STATS + 128 + c0] * (1.f / (float)BN_) - mu0 * mu0;
    float rs0 = rsqrtf(v0 + EPS_) * gamma[c0];
    float be0 = beta[c0];
    float mu1 = f[WS_STATS + c1] * (1.f / (float)BN_);
    float v1  = f[WS_STATS + 128 + c1] * (1.f / (float)BN_) - mu1 * mu1;
    float rs1 = rsqrtf(v1 + EPS_) * gamma[c1];
    float be1 = beta[c1];
    #pragma unroll
    for (int i = 0; i < 4; i++) {
      int row = quad * 4 + i;
      float z0 = (acc0[i] - mu0) * rs0 + be0;
      float z1 = (acc1[i] - mu1) * rs1 + be1;
      zs[row * D_ + c0] = f2b(z0 > 0.f ? z0 : 0.f);
      zs[row * D_ + c1] = f2b(z1 > 0.f ? z1 : 0.f);
    }
  }
  __syncthreads();

  // ---- GEMM2: recons tile [16 x 64], wave wv covers col-tile wv (of 4) ----
  {
    const int col = wv * 16 + m;
    float bias = br[col];
    f32x4 acc2 = {bias, bias, bias, bias};
    #pragma unroll
    for (int s = 0; s < 4; s++) {
      bf16x8 az = *(const bf16x8*)(zs + m * D_ + s * 32 + quad * 8);
      bf16x8 bz = *(const bf16x8*)(wrT + col * D_ + s * 32 + quad * 8);
      acc2 = __builtin_amdgcn_mfma_f32_16x16x32_bf16(az, bz, acc2, 0, 0, 0);
    }
    #pragma unroll
    for (int i = 0; i < 4; i++)
      out[(row0 + quad * 4 + i) * F_ + col] = acc2[i];
  }

  // ---- pred head: out_pred[row] = bp + z[row,:] . wp ----
  if (t < 16) {
    float acc = bp[0];
    #pragma unroll
    for (int k = 0; k < D_; k++) acc += b2f(zs[t * D_ + k]) * wp[k];
    out[OFF_PRED + row0 + t] = acc;
  }
}

// K5: weight_arr passthrough, vectorized fp32 copy
__global__ __launch_bounds__(256) void k_copyW(
    const float4* __restrict__ src, float4* __restrict__ dst)
{
  int i = blockIdx.x * 256 + threadIdx.x;
  dst[i] = src[i];
}

extern "C" void kernel_launch(void* const* d_in, const int* in_sizes, int n_in,
                              void* d_out, int out_size, void* d_ws, size_t ws_size,
                              hipStream_t stream) {
  const float* data  = (const float*)d_in[0];
  const int*   ei    = (const int*)d_in[1];
  const float* W     = (const float*)d_in[2];
  const float* lin_w = (const float*)d_in[3];
  // d_in[4] = gnn_bias: cancels exactly through training-mode BN
  const float* gamma = (const float*)d_in[5];
  const float* beta  = (const float*)d_in[6];
  const float* Wr    = (const float*)d_in[7];
  const float* br    = (const float*)d_in[8];
  const float* wp    = (const float*)d_in[9];
  const float* bp    = (const float*)d_in[10];
  float* out = (float*)d_out;
  float* ws  = (float*)d_ws;
  unsigned short* outs = (unsigned short*)d_out;   // XT @0, A @A_U16 (scratch)

  k_xt    <<<256,       256, 0, stream>>>(data, outs);
  k_attn  <<<1,         512, 0, stream>>>(W, ei, lin_w, Wr, ws, outs + A_U16);
  kB_gemm <<<B_ * 8,    256, 0, stream>>>(outs, ws);
  kC_stats<<<BN_ / 256, 256, 0, stream>>>(ws);
  kD_final<<<BN_ / 16,  256, 0, stream>>>(gamma, beta, br, wp, bp, ws, out);
  k_copyW <<<N_ * N_ / 1024, 256, 0, stream>>>((const float4*)W, (float4*)(out + OFF_W));
}

// Round 2
// 177.479 us; speedup vs baseline: 1.4281x; 1.3411x over previous
//
#include <hip/hip_runtime.h>
#include <hip/hip_bf16.h>

constexpr int B_  = 128;
constexpr int N_  = 512;
constexpr int F_  = 64;
constexpr int D_  = 128;
constexpr int E_  = 8192;
constexpr int BN_ = B_ * N_;              // 65536
constexpr float SLOPE = 0.2f;
constexpr float EPS_  = 1e-5f;
constexpr int OFF_PRED = BN_ * F_;        // 4194304 (elements)
constexpr int OFF_W    = OFF_PRED + BN_;  // 4259840

// workspace float-offsets
constexpr int WS_STATS = 16896;    // f[256]  (sum | sumsq)
constexpr int WS_WLT   = 25860;    // u16[128n][64k]   (bf16 Wl^T)
constexpr int WS_WRT   = 29956;    // u16[64n][128k]   (bf16 Wr^T)
constexpr int WS_Y     = 34052;    // bf16[BN*64]  (byte 136208, 16B aligned)

// scratch carved out of `out` (fully overwritten later by kD_final's recons):
//   XT bf16 [B][64 f][512 m]  at u16 offset 0         (4,194,304 u16 = 8.4 MB)
//   A  bf16 [512 n][512 m]    at u16 offset 4,194,304 (262,144 u16 = 0.5 MB)
// both end well below OFF_PRED floats (byte 16,777,216).
constexpr int A_U16 = 4194304;

typedef __attribute__((ext_vector_type(8))) short bf16x8;
typedef __attribute__((ext_vector_type(4))) float f32x4;

__device__ __forceinline__ float lrelu(float w) { return w > 0.f ? w : SLOPE * w; }
__device__ __forceinline__ unsigned short f2b(float v) {
  __hip_bfloat16 h = __float2bfloat16(v);
  return *(unsigned short*)&h;
}
__device__ __forceinline__ float b2f(unsigned short u) {
  __hip_bfloat16 h = *(__hip_bfloat16*)&u;
  return __bfloat162float(h);
}

// K0: fused prep, grid 576.
//   blocks [  0,256): XT[b][f][m] = bf16(X[b][m][f])  (block 0 also zeros stats)
//   blocks [256,288): wlT[n][k] = bf16(Wl[k][n])
//   blocks [288,320): wrT[n][k] = bf16(Wr[k][n])
//   blocks [320,576): W passthrough copy (float4)
__global__ __launch_bounds__(256) void k_pre(
    const float* __restrict__ X, const float* __restrict__ W,
    const float* __restrict__ Wl, const float* __restrict__ Wr,
    float* ws, unsigned short* __restrict__ outs, float* __restrict__ out)
{
  const int t = threadIdx.x;
  const int blk = blockIdx.x;
  if (blk < 256) {
    if (blk == 0) ws[WS_STATS + t] = 0.f;
    const int b = blk >> 1;
    const int m = ((blk & 1) << 8) + t;
    const float* xrow = X + ((size_t)b * N_ + m) * F_;
    unsigned short* xtb = outs + (size_t)b * (F_ * N_);
    #pragma unroll
    for (int f4 = 0; f4 < 16; f4++) {
      float4 v = *(const float4*)(xrow + f4 * 4);
      xtb[(f4 * 4 + 0) * N_ + m] = f2b(v.x);
      xtb[(f4 * 4 + 1) * N_ + m] = f2b(v.y);
      xtb[(f4 * 4 + 2) * N_ + m] = f2b(v.z);
      xtb[(f4 * 4 + 3) * N_ + m] = f2b(v.w);
    }
  } else if (blk < 288) {
    unsigned short* wlT = (unsigned short*)(ws + WS_WLT);
    int i = (blk - 256) * 256 + t;            // [0, 8192)
    int n = i >> 6, k = i & 63;
    wlT[i] = f2b(Wl[k * D_ + n]);
  } else if (blk < 320) {
    unsigned short* wrT = (unsigned short*)(ws + WS_WRT);
    int i = (blk - 288) * 256 + t;            // [0, 8192)
    int n = i >> 7, k = i & 127;
    wrT[i] = f2b(Wr[k * F_ + n]);
  } else {
    int i = (blk - 320) * 256 + t;            // [0, 65536)
    ((float4*)(out + OFF_W))[i] = ((const float4*)W)[i];
  }
}

// K1: dense softmax row build. One block per destination node.
// LDS edge-count histogram (exact duplicate handling: cnt * e^a), then
// masked row softmax over lrelu(W[row,:]) incl. self-loop -> bf16 A row.
__global__ __launch_bounds__(256) void k_soft(
    const float* __restrict__ W, const int* __restrict__ ei,
    unsigned short* __restrict__ Abf)
{
  __shared__ unsigned cnt[N_];
  __shared__ float red[8];
  const int t = threadIdx.x;
  const int row = blockIdx.x;
  const int wv = t >> 6;
  cnt[t] = 0u; cnt[t + 256] = 0u;
  __syncthreads();
  for (int e = t; e < E_; e += 256) {
    int d = ei[E_ + e];
    if (d == row) atomicAdd(&cnt[ei[e]], 1u);
  }
  __syncthreads();
  const int s0 = t, s1 = t + 256;
  const float a0 = lrelu(W[row * N_ + s0]);
  const float a1 = lrelu(W[row * N_ + s1]);
  const unsigned c0 = cnt[s0] + (s0 == row ? 1u : 0u);
  const unsigned c1 = cnt[s1] + (s1 == row ? 1u : 0u);
  float m = fmaxf(c0 ? a0 : -3.4e38f, c1 ? a1 : -3.4e38f);
  #pragma unroll
  for (int off = 32; off; off >>= 1) m = fmaxf(m, __shfl_xor(m, off));
  if ((t & 63) == 0) red[wv] = m;
  __syncthreads();
  const float amax = fmaxf(fmaxf(red[0], red[1]), fmaxf(red[2], red[3]));
  const float e0 = c0 ? (float)c0 * __expf(a0 - amax) : 0.f;
  const float e1 = c1 ? (float)c1 * __expf(a1 - amax) : 0.f;
  float sm = e0 + e1;
  #pragma unroll
  for (int off = 32; off; off >>= 1) sm += __shfl_xor(sm, off);
  if ((t & 63) == 0) red[4 + wv] = sm;
  __syncthreads();
  const float inv = 1.f / (red[4] + red[5] + red[6] + red[7]);
  Abf[row * N_ + s0] = f2b(e0 * inv);
  Abf[row * N_ + s1] = f2b(e1 * inv);
}

// K2: aggregation as dense MFMA GEMM.  Y^T_b = XT_b(64x512) @ A^T  =>
// Y[r][f] bf16 in ws (same layout kC/kD consume).  Both fragment streams are
// contiguous global reads (XT rows / A rows), no LDS, no barriers.
// grid = 128 b x 8 n-slices; 4 waves; wave wv = f-tile, 4 n-tiles each.
__global__ __launch_bounds__(256) void kB_gemm(
    const unsigned short* __restrict__ XT, float* ws)
{
  unsigned short* Yb = (unsigned short*)((float*)ws + WS_Y);
  const unsigned short* Abf = XT + A_U16;
  const int t = threadIdx.x;
  const int wv = t >> 6, lane = t & 63;
  const int m = lane & 15, quad = lane >> 4;
  const int b = blockIdx.x >> 3, ns = blockIdx.x & 7;
  const int n0 = ns * 64;
  const unsigned short* af = XT + (size_t)b * (F_ * N_) + (wv * 16 + m) * N_;
  f32x4 acc[4] = {{0.f,0.f,0.f,0.f},{0.f,0.f,0.f,0.f},
                  {0.f,0.f,0.f,0.f},{0.f,0.f,0.f,0.f}};
  #pragma unroll 4
  for (int kk = 0; kk < 16; kk++) {
    const int k0 = kk * 32 + quad * 8;
    bf16x8 a = *(const bf16x8*)(af + k0);
    #pragma unroll
    for (int nt = 0; nt < 4; nt++) {
      bf16x8 bb = *(const bf16x8*)(Abf + (n0 + nt * 16 + m) * N_ + k0);
      acc[nt] = __builtin_amdgcn_mfma_f32_16x16x32_bf16(a, bb, acc[nt], 0, 0, 0);
    }
  }
  // D-layout: col(lane&15) = n within tile, row(quad*4+i) = f  ->  pack 4
  // consecutive f as ushort4 per lane, store into Y[r][f].
  const size_t rb = (size_t)b * N_ + n0 + m;
  #pragma unroll
  for (int nt = 0; nt < 4; nt++) {
    ushort4 y4;
    y4.x = f2b(acc[nt][0]); y4.y = f2b(acc[nt][1]);
    y4.z = f2b(acc[nt][2]); y4.w = f2b(acc[nt][3]);
    *(ushort4*)(Yb + (rb + nt * 16) * F_ + wv * 16 + quad * 4) = y4;
  }
}

// K3: BN stats via MFMA (h = Y @ Wl on 16x16x32 bf16 matrix cores).
// 256 blocks x 256 rows; per-lane sum/sumsq, quad-shuffle reduce, atomics.
__global__ __launch_bounds__(256) void kC_stats(float* ws)
{
  float* f = (float*)ws;
  const unsigned short* Yb  = (const unsigned short*)(f + WS_Y);
  const unsigned short* wlT = (const unsigned short*)(f + WS_WLT);
  const int t = threadIdx.x;
  const int wv = t >> 6, lane = t & 63;
  const int m = lane & 15, quad = lane >> 4;
  const int T0 = 2 * wv, T1 = 2 * wv + 1;   // column tiles (of 8)
  // B-fragments are row-invariant: load once
  bf16x8 b00 = *(const bf16x8*)(wlT + (T0 * 16 + m) * 64 +  0 + quad * 8);
  bf16x8 b01 = *(const bf16x8*)(wlT + (T0 * 16 + m) * 64 + 32 + quad * 8);
  bf16x8 b10 = *(const bf16x8*)(wlT + (T1 * 16 + m) * 64 +  0 + quad * 8);
  bf16x8 b11 = *(const bf16x8*)(wlT + (T1 * 16 + m) * 64 + 32 + quad * 8);
  float sum0 = 0.f, sq0 = 0.f, sum1 = 0.f, sq1 = 0.f;
  const int rowblk = blockIdx.x * 256;
  for (int st = 0; st < 16; st++) {
    const int rowbase = rowblk + st * 16;
    bf16x8 a0 = *(const bf16x8*)(Yb + (size_t)(rowbase + m) * 64 +  0 + quad * 8);
    bf16x8 a1 = *(const bf16x8*)(Yb + (size_t)(rowbase + m) * 64 + 32 + quad * 8);
    f32x4 acc0 = {0.f, 0.f, 0.f, 0.f}, acc1 = {0.f, 0.f, 0.f, 0.f};
    acc0 = __builtin_amdgcn_mfma_f32_16x16x32_bf16(a0, b00, acc0, 0, 0, 0);
    acc0 = __builtin_amdgcn_mfma_f32_16x16x32_bf16(a1, b01, acc0, 0, 0, 0);
    acc1 = __builtin_amdgcn_mfma_f32_16x16x32_bf16(a0, b10, acc1, 0, 0, 0);
    acc1 = __builtin_amdgcn_mfma_f32_16x16x32_bf16(a1, b11, acc1, 0, 0, 0);
    #pragma unroll
    for (int i = 0; i < 4; i++) {
      sum0 += acc0[i]; sq0 += acc0[i] * acc0[i];
      sum1 += acc1[i]; sq1 += acc1[i] * acc1[i];
    }
  }
  // reduce across quads (rows) -> per-column totals in lanes 0..15
  sum0 += __shfl_xor(sum0, 16); sum0 += __shfl_xor(sum0, 32);
  sq0  += __shfl_xor(sq0, 16);  sq0  += __shfl_xor(sq0, 32);
  sum1 += __shfl_xor(sum1, 16); sum1 += __shfl_xor(sum1, 32);
  sq1  += __shfl_xor(sq1, 16);  sq1  += __shfl_xor(sq1, 32);
  if (quad == 0) {
    atomicAdd(&f[WS_STATS + T0 * 16 + m], sum0);
    atomicAdd(&f[WS_STATS + 128 + T0 * 16 + m], sq0);
    atomicAdd(&f[WS_STATS + T1 * 16 + m], sum1);
    atomicAdd(&f[WS_STATS + 128 + T1 * 16 + m], sq1);
  }
}

// K4: MFMA epilogue: h = Y@Wl -> BN+ReLU -> z (LDS bf16) -> z@Wr + both heads.
__global__ __launch_bounds__(256) void kD_final(
    const float* __restrict__ gamma, const float* __restrict__ beta,
    const float* __restrict__ br, const float* __restrict__ wp,
    const float* __restrict__ bp, float* ws, float* __restrict__ out)
{
  __shared__ unsigned short zs[16 * D_];   // 4 KB bf16 z-tile
  float* f = (float*)ws;
  const unsigned short* Yb  = (const unsigned short*)(f + WS_Y);
  const unsigned short* wlT = (const unsigned short*)(f + WS_WLT);
  const unsigned short* wrT = (const unsigned short*)(f + WS_WRT);
  const int t = threadIdx.x;
  const int wv = t >> 6, lane = t & 63;
  const int m = lane & 15, quad = lane >> 4;
  const size_t row0 = (size_t)blockIdx.x * 16;

  // ---- GEMM1: h tile [16 x 128], wave wv covers col-tiles 2wv, 2wv+1 ----
  const int T0 = 2 * wv, T1 = 2 * wv + 1;
  bf16x8 a0 = *(const bf16x8*)(Yb + (row0 + m) * 64 +  0 + quad * 8);
  bf16x8 a1 = *(const bf16x8*)(Yb + (row0 + m) * 64 + 32 + quad * 8);
  bf16x8 b00 = *(const bf16x8*)(wlT + (T0 * 16 + m) * 64 +  0 + quad * 8);
  bf16x8 b01 = *(const bf16x8*)(wlT + (T0 * 16 + m) * 64 + 32 + quad * 8);
  bf16x8 b10 = *(const bf16x8*)(wlT + (T1 * 16 + m) * 64 +  0 + quad * 8);
  bf16x8 b11 = *(const bf16x8*)(wlT + (T1 * 16 + m) * 64 + 32 + quad * 8);
  f32x4 acc0 = {0.f, 0.f, 0.f, 0.f}, acc1 = {0.f, 0.f, 0.f, 0.f};
  acc0 = __builtin_amdgcn_mfma_f32_16x16x32_bf16(a0, b00, acc0, 0, 0, 0);
  acc0 = __builtin_amdgcn_mfma_f32_16x16x32_bf16(a1, b01, acc0, 0, 0, 0);
  acc1 = __builtin_amdgcn_mfma_f32_16x16x32_bf16(a0, b10, acc1, 0, 0, 0);
  acc1 = __builtin_amdgcn_mfma_f32_16x16x32_bf16(a1, b11, acc1, 0, 0, 0);

  // ---- BN + ReLU -> z (bf16 in LDS) ----
  {
    int c0 = T0 * 16 + m, c1 = T1 * 16 + m;
    float mu0 = f[WS_STATS + c0] * (1.f / (float)BN_);
    float v0  = f[WS_STATS + 128 + c0] * (1.f / (float)BN_) - mu0 * mu0;
    float rs0 = rsqrtf(v0 + EPS_) * gamma[c0];
    float be0 = beta[c0];
    float mu1 = f[WS_STATS + c1] * (1.f / (float)BN_);
    float v1  = f[WS_STATS + 128 + c1] * (1.f / (float)BN_) - mu1 * mu1;
    float rs1 = rsqrtf(v1 + EPS_) * gamma[c1];
    float be1 = beta[c1];
    #pragma unroll
    for (int i = 0; i < 4; i++) {
      int row = quad * 4 + i;
      float z0 = (acc0[i] - mu0) * rs0 + be0;
      float z1 = (acc1[i] - mu1) * rs1 + be1;
      zs[row * D_ + c0] = f2b(z0 > 0.f ? z0 : 0.f);
      zs[row * D_ + c1] = f2b(z1 > 0.f ? z1 : 0.f);
    }
  }
  __syncthreads();

  // ---- GEMM2: recons tile [16 x 64], wave wv covers col-tile wv (of 4) ----
  {
    const int col = wv * 16 + m;
    float bias = br[col];
    f32x4 acc2 = {bias, bias, bias, bias};
    #pragma unroll
    for (int s = 0; s < 4; s++) {
      bf16x8 az = *(const bf16x8*)(zs + m * D_ + s * 32 + quad * 8);
      bf16x8 bz = *(const bf16x8*)(wrT + col * D_ + s * 32 + quad * 8);
      acc2 = __builtin_amdgcn_mfma_f32_16x16x32_bf16(az, bz, acc2, 0, 0, 0);
    }
    #pragma unroll
    for (int i = 0; i < 4; i++)
      out[(row0 + quad * 4 + i) * F_ + col] = acc2[i];
  }

  // ---- pred head: out_pred[row] = bp + z[row,:] . wp ----
  if (t < 16) {
    float acc = bp[0];
    #pragma unroll
    for (int k = 0; k < D_; k++) acc += b2f(zs[t * D_ + k]) * wp[k];
    out[OFF_PRED + row0 + t] = acc;
  }
}

extern "C" void kernel_launch(void* const* d_in, const int* in_sizes, int n_in,
                              void* d_out, int out_size, void* d_ws, size_t ws_size,
                              hipStream_t stream) {
  const float* data  = (const float*)d_in[0];
  const int*   ei    = (const int*)d_in[1];
  const float* W     = (const float*)d_in[2];
  const float* lin_w = (const float*)d_in[3];
  // d_in[4] = gnn_bias: cancels exactly through training-mode BN
  const float* gamma = (const float*)d_in[5];
  const float* beta  = (const float*)d_in[6];
  const float* Wr    = (const float*)d_in[7];
  const float* br    = (const float*)d_in[8];
  const float* wp    = (const float*)d_in[9];
  const float* bp    = (const float*)d_in[10];
  float* out = (float*)d_out;
  float* ws  = (float*)d_ws;
  unsigned short* outs = (unsigned short*)d_out;   // XT @0, A @A_U16 (scratch)

  k_pre   <<<576,       256, 0, stream>>>(data, W, lin_w, Wr, ws, outs, out);
  k_soft  <<<N_,        256, 0, stream>>>(W, ei, outs + A_U16);
  kB_gemm <<<B_ * 8,    256, 0, stream>>>(outs, ws);
  kC_stats<<<BN_ / 256, 256, 0, stream>>>(ws);
  kD_final<<<BN_ / 16,  256, 0, stream>>>(gamma, beta, br, wp, bp, ws, out);
}

// Round 3
// 167.461 us; speedup vs baseline: 1.5136x; 1.0598x over previous
//
#include <hip/hip_runtime.h>
#include <hip/hip_bf16.h>

constexpr int B_  = 128;
constexpr int N_  = 512;
constexpr int F_  = 64;
constexpr int D_  = 128;
constexpr int E_  = 8192;
constexpr int BN_ = B_ * N_;              // 65536
constexpr float SLOPE = 0.2f;
constexpr float EPS_  = 1e-5f;
constexpr int OFF_PRED = BN_ * F_;        // 4194304 (elements)
constexpr int OFF_W    = OFF_PRED + BN_;  // 4259840

// workspace float-offsets (ws = 256 MiB per the fillBuffer WRITE_SIZE)
constexpr int WS_STATS = 16896;    // f[256]  (sum | sumsq)
constexpr int WS_WLT   = 25860;    // u16[128n][64k]   (bf16 Wl^T)
constexpr int WS_WRT   = 29956;    // u16[64n][128k]   (bf16 Wr^T)
constexpr int WS_H     = 34052;    // bf16[BN*128] = 16.7 MB (byte 136208, 16B aligned)

// scratch carved out of `out` (fully overwritten later by kD's recons):
//   XT bf16 [B][64 f][512 m]  at u16 offset 0
//   A  bf16 [512 n][512 m]    at u16 offset 4,194,304
constexpr int A_U16 = 4194304;

typedef __attribute__((ext_vector_type(8))) short bf16x8;
typedef __attribute__((ext_vector_type(4))) float f32x4;

__device__ __forceinline__ float lrelu(float w) { return w > 0.f ? w : SLOPE * w; }
__device__ __forceinline__ unsigned short f2b(float v) {
  __hip_bfloat16 h = __float2bfloat16(v);
  return *(unsigned short*)&h;
}
__device__ __forceinline__ float b2f(unsigned short u) {
  __hip_bfloat16 h = *(__hip_bfloat16*)&u;
  return __bfloat162float(h);
}

// K0: fused prep, grid 1088.
//   [   0, 256): XT[b][f][m] = bf16(X[b][m][f])  (block 0 zeros stats)
//   [ 256, 288): wlT[n][k] = bf16(Wl[k][n])
//   [ 288, 320): wrT[n][k] = bf16(Wr[k][n])
//   [ 320, 576): W passthrough copy (float4)
//   [ 576,1088): dense softmax row build (one block per dst node)
__global__ __launch_bounds__(256) void k_prep(
    const float* __restrict__ X, const float* __restrict__ W,
    const float* __restrict__ Wl, const float* __restrict__ Wr,
    const int* __restrict__ ei,
    float* ws, unsigned short* __restrict__ outs, float* __restrict__ out)
{
  const int t = threadIdx.x;
  const int blk = blockIdx.x;
  if (blk < 256) {
    if (blk == 0) ws[WS_STATS + t] = 0.f;
    const int b = blk >> 1;
    const int m = ((blk & 1) << 8) + t;
    const float* xrow = X + ((size_t)b * N_ + m) * F_;
    unsigned short* xtb = outs + (size_t)b * (F_ * N_);
    #pragma unroll
    for (int f4 = 0; f4 < 16; f4++) {
      float4 v = *(const float4*)(xrow + f4 * 4);
      xtb[(f4 * 4 + 0) * N_ + m] = f2b(v.x);
      xtb[(f4 * 4 + 1) * N_ + m] = f2b(v.y);
      xtb[(f4 * 4 + 2) * N_ + m] = f2b(v.z);
      xtb[(f4 * 4 + 3) * N_ + m] = f2b(v.w);
    }
  } else if (blk < 288) {
    unsigned short* wlT = (unsigned short*)(ws + WS_WLT);
    int i = (blk - 256) * 256 + t;            // [0, 8192)
    int n = i >> 6, k = i & 63;
    wlT[i] = f2b(Wl[k * D_ + n]);
  } else if (blk < 320) {
    unsigned short* wrT = (unsigned short*)(ws + WS_WRT);
    int i = (blk - 288) * 256 + t;            // [0, 8192)
    int n = i >> 7, k = i & 127;
    wrT[i] = f2b(Wr[k * F_ + n]);
  } else if (blk < 576) {
    int i = (blk - 320) * 256 + t;            // [0, 65536)
    ((float4*)(out + OFF_W))[i] = ((const float4*)W)[i];
  } else {
    // dense masked row softmax (exact duplicate handling: cnt * e^a)
    __shared__ unsigned cnt[N_];
    __shared__ float red[8];
    unsigned short* Abf = outs + A_U16;
    const int row = blk - 576;
    const int wv = t >> 6;
    cnt[t] = 0u; cnt[t + 256] = 0u;
    __syncthreads();
    for (int e = t; e < E_; e += 256) {
      int d = ei[E_ + e];
      if (d == row) atomicAdd(&cnt[ei[e]], 1u);
    }
    __syncthreads();
    const int s0 = t, s1 = t + 256;
    const float a0 = lrelu(W[row * N_ + s0]);
    const float a1 = lrelu(W[row * N_ + s1]);
    const unsigned c0 = cnt[s0] + (s0 == row ? 1u : 0u);
    const unsigned c1 = cnt[s1] + (s1 == row ? 1u : 0u);
    float m = fmaxf(c0 ? a0 : -3.4e38f, c1 ? a1 : -3.4e38f);
    #pragma unroll
    for (int off = 32; off; off >>= 1) m = fmaxf(m, __shfl_xor(m, off));
    if ((t & 63) == 0) red[wv] = m;
    __syncthreads();
    const float amax = fmaxf(fmaxf(red[0], red[1]), fmaxf(red[2], red[3]));
    const float e0 = c0 ? (float)c0 * __expf(a0 - amax) : 0.f;
    const float e1 = c1 ? (float)c1 * __expf(a1 - amax) : 0.f;
    float sm = e0 + e1;
    #pragma unroll
    for (int off = 32; off; off >>= 1) sm += __shfl_xor(sm, off);
    if ((t & 63) == 0) red[4 + wv] = sm;
    __syncthreads();
    const float inv = 1.f / (red[4] + red[5] + red[6] + red[7]);
    Abf[row * N_ + s0] = f2b(e0 * inv);
    Abf[row * N_ + s1] = f2b(e1 * inv);
  }
}

// K1: fused aggregation + projection + BN stats.
//   Y-tile (64n x 64f) = A-slice @ XT_b via MFMA  -> swizzled LDS
//   h-tile (64n x 128d) = Y @ Wl via MFMA (K=64 fully inside block)
//   stats: per-column sum/sumsq from f32 acc -> global atomics
//   H bf16 [BN x 128] written once (coalesced via LDS bounce).
// grid = 128 b x 8 n-slices; 4 waves: Y-phase wave = f-tile, h-phase wave = 32 d's.
__global__ __launch_bounds__(256) void kBC(
    const unsigned short* __restrict__ XT, float* ws)
{
  __shared__ __align__(16) unsigned short ys[64 * 64];    // Y tile, XOR-swizzled
  __shared__ __align__(16) unsigned short hs[64 * 128];   // h tile, XOR-swizzled
  float* f = ws;
  unsigned short* H = (unsigned short*)(ws + WS_H);
  const unsigned short* wlT = (const unsigned short*)(ws + WS_WLT);
  const unsigned short* Abf = XT + A_U16;
  const int t = threadIdx.x;
  const int wv = t >> 6, lane = t & 63;
  const int m = lane & 15, quad = lane >> 4;
  const int b = blockIdx.x >> 3, ns = blockIdx.x & 7;
  const int n0 = ns * 64;

  // ---- Y GEMM: Y^T[f][n] = XT_b[f][:] . A[n][:] ----
  const unsigned short* af = XT + (size_t)b * (F_ * N_) + (wv * 16 + m) * N_;
  f32x4 acc[4] = {{0.f,0.f,0.f,0.f},{0.f,0.f,0.f,0.f},
                  {0.f,0.f,0.f,0.f},{0.f,0.f,0.f,0.f}};
  #pragma unroll 4
  for (int kk = 0; kk < 16; kk++) {
    const int k0 = kk * 32 + quad * 8;
    bf16x8 a = *(const bf16x8*)(af + k0);
    #pragma unroll
    for (int nt = 0; nt < 4; nt++) {
      bf16x8 bb = *(const bf16x8*)(Abf + (n0 + nt * 16 + m) * N_ + k0);
      acc[nt] = __builtin_amdgcn_mfma_f32_16x16x32_bf16(a, bb, acc[nt], 0, 0, 0);
    }
  }
  // store Y tile to LDS: ys[n][f ^ ((n&7)<<3)], 8B-block-preserving swizzle
  #pragma unroll
  for (int nt = 0; nt < 4; nt++) {
    const int n = nt * 16 + m;
    const int c = (wv * 16 + quad * 4) ^ ((n & 7) << 3);
    ushort4 y4;
    y4.x = f2b(acc[nt][0]); y4.y = f2b(acc[nt][1]);
    y4.z = f2b(acc[nt][2]); y4.w = f2b(acc[nt][3]);
    *(ushort4*)(ys + n * 64 + c) = y4;
  }
  __syncthreads();

  // ---- h GEMM: h[n][d] = sum_f Y[n][f] Wl[f][d]; wave wv owns d0=wv*32 ----
  const int d0 = wv * 32;
  bf16x8 bw00 = *(const bf16x8*)(wlT + (d0 + m) * 64 + quad * 8);
  bf16x8 bw01 = *(const bf16x8*)(wlT + (d0 + m) * 64 + 32 + quad * 8);
  bf16x8 bw10 = *(const bf16x8*)(wlT + (d0 + 16 + m) * 64 + quad * 8);
  bf16x8 bw11 = *(const bf16x8*)(wlT + (d0 + 16 + m) * 64 + 32 + quad * 8);
  f32x4 acch[4][2];
  #pragma unroll
  for (int nt = 0; nt < 4; nt++) {
    acch[nt][0] = f32x4{0.f,0.f,0.f,0.f};
    acch[nt][1] = f32x4{0.f,0.f,0.f,0.f};
  }
  #pragma unroll
  for (int nt = 0; nt < 4; nt++) {
    const int n2 = nt * 16 + m;
    const int sw = (n2 & 7) << 3;
    bf16x8 aA = *(const bf16x8*)(ys + n2 * 64 + ((quad * 8) ^ sw));
    bf16x8 aB = *(const bf16x8*)(ys + n2 * 64 + ((32 + quad * 8) ^ sw));
    acch[nt][0] = __builtin_amdgcn_mfma_f32_16x16x32_bf16(aA, bw00, acch[nt][0], 0, 0, 0);
    acch[nt][0] = __builtin_amdgcn_mfma_f32_16x16x32_bf16(aB, bw01, acch[nt][0], 0, 0, 0);
    acch[nt][1] = __builtin_amdgcn_mfma_f32_16x16x32_bf16(aA, bw10, acch[nt][1], 0, 0, 0);
    acch[nt][1] = __builtin_amdgcn_mfma_f32_16x16x32_bf16(aB, bw11, acch[nt][1], 0, 0, 0);
  }

  // ---- stats (f32) + h-tile scatter into swizzled LDS ----
  float sm0 = 0.f, sq0 = 0.f, sm1 = 0.f, sq1 = 0.f;
  #pragma unroll
  for (int nt = 0; nt < 4; nt++) {
    #pragma unroll
    for (int i = 0; i < 4; i++) {
      const int n = nt * 16 + quad * 4 + i;
      const int swn = (n & 7) << 3;
      float v0 = acch[nt][0][i], v1 = acch[nt][1][i];
      sm0 += v0; sq0 += v0 * v0;
      sm1 += v1; sq1 += v1 * v1;
      hs[n * 128 + ((d0 + m) ^ swn)]      = f2b(v0);
      hs[n * 128 + ((d0 + 16 + m) ^ swn)] = f2b(v1);
    }
  }
  sm0 += __shfl_xor(sm0, 16); sm0 += __shfl_xor(sm0, 32);
  sq0 += __shfl_xor(sq0, 16); sq0 += __shfl_xor(sq0, 32);
  sm1 += __shfl_xor(sm1, 16); sm1 += __shfl_xor(sm1, 32);
  sq1 += __shfl_xor(sq1, 16); sq1 += __shfl_xor(sq1, 32);
  if (quad == 0) {
    atomicAdd(&f[WS_STATS + d0 + m], sm0);
    atomicAdd(&f[WS_STATS + 128 + d0 + m], sq0);
    atomicAdd(&f[WS_STATS + d0 + 16 + m], sm1);
    atomicAdd(&f[WS_STATS + 128 + d0 + 16 + m], sq1);
  }
  __syncthreads();

  // ---- coalesced H write (un-swizzle via 16B block reads) ----
  unsigned short* Hb = H + ((size_t)b * N_ + n0) * D_;
  #pragma unroll
  for (int k = 0; k < 4; k++) {
    const int cidx = k * 256 + t;                 // 1024 x 16B chunks
    const int n = cidx >> 4, cb = (cidx & 15) << 3;
    *(uint4*)(Hb + n * 128 + cb) =
        *(const uint4*)(hs + n * 128 + (cb ^ ((n & 7) << 3)));
  }
}

// K2: epilogue: read H, BN+ReLU (z = h*rs + zb), zs -> GEMM2 + pred head.
__global__ __launch_bounds__(256) void kD(
    const float* __restrict__ gamma, const float* __restrict__ beta,
    const float* __restrict__ br, const float* __restrict__ wp,
    const float* __restrict__ bp, float* ws, float* __restrict__ out)
{
  constexpr int LDP = 136;                        // zs row pad: breaks 256B stride
  __shared__ __align__(16) unsigned short zs[16 * LDP];
  __shared__ float rsL[D_], zbL[D_], wpL[D_];
  float* f = ws;
  const unsigned short* H   = (const unsigned short*)(f + WS_H);
  const unsigned short* wrT = (const unsigned short*)(f + WS_WRT);
  const int t = threadIdx.x;
  const int wv = t >> 6, lane = t & 63;
  const int m = lane & 15, quad = lane >> 4;
  const size_t row0 = (size_t)blockIdx.x * 16;

  if (t < 128) {
    float mu  = f[WS_STATS + t] * (1.f / (float)BN_);
    float var = f[WS_STATS + 128 + t] * (1.f / (float)BN_) - mu * mu;
    float rg  = rsqrtf(var + EPS_) * gamma[t];
    rsL[t] = rg;
    zbL[t] = beta[t] - mu * rg;
    wpL[t] = wp[t];
  }
  __syncthreads();

  // ---- BN + ReLU: each thread handles 8 consecutive d of one row ----
  {
    const int r = t >> 4, c8 = (t & 15) << 3;
    bf16x8 h8 = *(const bf16x8*)(H + (row0 + r) * D_ + c8);
    ushort4 za, zb4;
    #pragma unroll
    for (int j = 0; j < 8; j++) {
      float z = fmaf(b2f((unsigned short)h8[j]), rsL[c8 + j], zbL[c8 + j]);
      z = z > 0.f ? z : 0.f;
      unsigned short zb16 = f2b(z);
      if (j < 4) ((unsigned short*)&za)[j] = zb16;
      else       ((unsigned short*)&zb4)[j - 4] = zb16;
    }
    *(ushort4*)(zs + r * LDP + c8)     = za;
    *(ushort4*)(zs + r * LDP + c8 + 4) = zb4;
  }
  __syncthreads();

  // ---- GEMM2: recons tile [16 x 64], wave wv -> col-tile wv ----
  {
    const int col = wv * 16 + m;
    float bias = br[col];
    f32x4 acc2 = {bias, bias, bias, bias};
    #pragma unroll
    for (int s = 0; s < 4; s++) {
      bf16x8 az = *(const bf16x8*)(zs + m * LDP + s * 32 + quad * 8);
      bf16x8 bz = *(const bf16x8*)(wrT + col * D_ + s * 32 + quad * 8);
      acc2 = __builtin_amdgcn_mfma_f32_16x16x32_bf16(az, bz, acc2, 0, 0, 0);
    }
    #pragma unroll
    for (int i = 0; i < 4; i++)
      out[(row0 + quad * 4 + i) * F_ + col] = acc2[i];
  }

  // ---- pred head: 8 lanes per row, 16 d each, shuffle reduce ----
  if (t < 128) {
    const int r = t >> 3, j = t & 7;
    float a = 0.f;
    #pragma unroll
    for (int k = 0; k < 16; k++) {
      const int d = j * 16 + k;
      a += b2f(zs[r * LDP + d]) * wpL[d];
    }
    a += __shfl_xor(a, 1); a += __shfl_xor(a, 2); a += __shfl_xor(a, 4);
    if (j == 0) out[OFF_PRED + row0 + r] = a + bp[0];
  }
}

extern "C" void kernel_launch(void* const* d_in, const int* in_sizes, int n_in,
                              void* d_out, int out_size, void* d_ws, size_t ws_size,
                              hipStream_t stream) {
  const float* data  = (const float*)d_in[0];
  const int*   ei    = (const int*)d_in[1];
  const float* W     = (const float*)d_in[2];
  const float* lin_w = (const float*)d_in[3];
  // d_in[4] = gnn_bias: cancels exactly through training-mode BN
  const float* gamma = (const float*)d_in[5];
  const float* beta  = (const float*)d_in[6];
  const float* Wr    = (const float*)d_in[7];
  const float* br    = (const float*)d_in[8];
  const float* wp    = (const float*)d_in[9];
  const float* bp    = (const float*)d_in[10];
  float* out = (float*)d_out;
  float* ws  = (float*)d_ws;
  unsigned short* outs = (unsigned short*)d_out;   // XT @0, A @A_U16 (scratch)

  k_prep <<<1088,      256, 0, stream>>>(data, W, lin_w, Wr, ei, ws, outs, out);
  kBC    <<<B_ * 8,    256, 0, stream>>>(outs, ws);
  kD     <<<BN_ / 16,  256, 0, stream>>>(gamma, beta, br, wp, bp, ws, out);
}

// Round 4
// 156.935 us; speedup vs baseline: 1.6151x; 1.0671x over previous
//
#include <hip/hip_runtime.h>
#include <hip/hip_bf16.h>

constexpr int B_  = 128;
constexpr int N_  = 512;
constexpr int F_  = 64;
constexpr int D_  = 128;
constexpr int E_  = 8192;
constexpr int BN_ = B_ * N_;              // 65536
constexpr float SLOPE = 0.2f;
constexpr float EPS_  = 1e-5f;
constexpr int OFF_PRED = BN_ * F_;        // 4194304 (elements)
constexpr int OFF_W    = OFF_PRED + BN_;  // 4259840

// workspace float-offsets (ws = 256 MiB per the fillBuffer WRITE_SIZE)
constexpr int WS_STATS = 16896;    // f[16][256]  bucketed (sum | sumsq), 4096 floats
constexpr int NBKT     = 16;
constexpr int WS_WLT   = 25860;    // u16[128n][64k]   (bf16 Wl^T)
constexpr int WS_WRT   = 29956;    // u16[64n][128k]   (bf16 Wr^T)
constexpr int WS_H     = 34052;    // bf16[BN*128] = 16.7 MB (byte 136208, 16B aligned)

// scratch carved out of `out` (fully overwritten later by kD's recons):
//   XT bf16 [B][64 f][512 m]  at u16 offset 0
//   A  bf16 [512 n][512 m]    at u16 offset 4,194,304
constexpr int A_U16 = 4194304;

typedef __attribute__((ext_vector_type(8))) short bf16x8;
typedef __attribute__((ext_vector_type(4))) float f32x4;

__device__ __forceinline__ float lrelu(float w) { return w > 0.f ? w : SLOPE * w; }
__device__ __forceinline__ unsigned short f2b(float v) {
  __hip_bfloat16 h = __float2bfloat16(v);
  return *(unsigned short*)&h;
}
__device__ __forceinline__ float b2f(unsigned short u) {
  __hip_bfloat16 h = *(__hip_bfloat16*)&u;
  return __bfloat162float(h);
}

// K0: fused prep, grid 1088.
//   [   0, 256): XT[b][f][m] = bf16(X[b][m][f])  (block 0 zeros stat buckets)
//   [ 256, 288): wlT[n][k] = bf16(Wl[k][n])
//   [ 288, 320): wrT[n][k] = bf16(Wr[k][n])
//   [ 320, 576): W passthrough copy (float4)
//   [ 576,1088): dense softmax row build (one block per dst node)
__global__ __launch_bounds__(256) void k_prep(
    const float* __restrict__ X, const float* __restrict__ W,
    const float* __restrict__ Wl, const float* __restrict__ Wr,
    const int* __restrict__ ei,
    float* ws, unsigned short* __restrict__ outs, float* __restrict__ out)
{
  const int t = threadIdx.x;
  const int blk = blockIdx.x;
  if (blk < 256) {
    if (blk == 0) {
      #pragma unroll
      for (int i = 0; i < NBKT; i++) ws[WS_STATS + i * 256 + t] = 0.f;
    }
    const int b = blk >> 1;
    const int m = ((blk & 1) << 8) + t;
    const float* xrow = X + ((size_t)b * N_ + m) * F_;
    unsigned short* xtb = outs + (size_t)b * (F_ * N_);
    #pragma unroll
    for (int f4 = 0; f4 < 16; f4++) {
      float4 v = *(const float4*)(xrow + f4 * 4);
      xtb[(f4 * 4 + 0) * N_ + m] = f2b(v.x);
      xtb[(f4 * 4 + 1) * N_ + m] = f2b(v.y);
      xtb[(f4 * 4 + 2) * N_ + m] = f2b(v.z);
      xtb[(f4 * 4 + 3) * N_ + m] = f2b(v.w);
    }
  } else if (blk < 288) {
    unsigned short* wlT = (unsigned short*)(ws + WS_WLT);
    int i = (blk - 256) * 256 + t;            // [0, 8192)
    int n = i >> 6, k = i & 63;
    wlT[i] = f2b(Wl[k * D_ + n]);
  } else if (blk < 320) {
    unsigned short* wrT = (unsigned short*)(ws + WS_WRT);
    int i = (blk - 288) * 256 + t;            // [0, 8192)
    int n = i >> 7, k = i & 127;
    wrT[i] = f2b(Wr[k * F_ + n]);
  } else if (blk < 576) {
    int i = (blk - 320) * 256 + t;            // [0, 65536)
    ((float4*)(out + OFF_W))[i] = ((const float4*)W)[i];
  } else {
    // dense masked row softmax (exact duplicate handling: cnt * e^a)
    __shared__ unsigned cnt[N_];
    __shared__ float red[8];
    unsigned short* Abf = outs + A_U16;
    const int row = blk - 576;
    const int wv = t >> 6;
    cnt[t] = 0u; cnt[t + 256] = 0u;
    __syncthreads();
    for (int e = t; e < E_; e += 256) {
      int d = ei[E_ + e];
      if (d == row) atomicAdd(&cnt[ei[e]], 1u);
    }
    __syncthreads();
    const int s0 = t, s1 = t + 256;
    const float a0 = lrelu(W[row * N_ + s0]);
    const float a1 = lrelu(W[row * N_ + s1]);
    const unsigned c0 = cnt[s0] + (s0 == row ? 1u : 0u);
    const unsigned c1 = cnt[s1] + (s1 == row ? 1u : 0u);
    float m = fmaxf(c0 ? a0 : -3.4e38f, c1 ? a1 : -3.4e38f);
    #pragma unroll
    for (int off = 32; off; off >>= 1) m = fmaxf(m, __shfl_xor(m, off));
    if ((t & 63) == 0) red[wv] = m;
    __syncthreads();
    const float amax = fmaxf(fmaxf(red[0], red[1]), fmaxf(red[2], red[3]));
    const float e0 = c0 ? (float)c0 * __expf(a0 - amax) : 0.f;
    const float e1 = c1 ? (float)c1 * __expf(a1 - amax) : 0.f;
    float sm = e0 + e1;
    #pragma unroll
    for (int off = 32; off; off >>= 1) sm += __shfl_xor(sm, off);
    if ((t & 63) == 0) red[4 + wv] = sm;
    __syncthreads();
    const float inv = 1.f / (red[4] + red[5] + red[6] + red[7]);
    Abf[row * N_ + s0] = f2b(e0 * inv);
    Abf[row * N_ + s1] = f2b(e1 * inv);
  }
}

// K1: fused aggregation + projection + BN stats.
//   Y-tile (64n x 64f) = A-slice @ XT_b via MFMA  -> swizzled LDS
//   h-tile (64n x 128d) = Y @ Wl via MFMA (K=64 fully inside block)
//   stats: per-column sum/sumsq from f32 acc -> bucketed atomics AT KERNEL END
//   H bf16 [BN x 128] written once (coalesced via LDS bounce).
// grid = 128 b x 8 n-slices; 4 waves: Y-phase wave = f-tile, h-phase wave = 32 d's.
__global__ __launch_bounds__(256) void kBC(
    const unsigned short* __restrict__ XT, float* ws)
{
  __shared__ __align__(16) unsigned short ys[64 * 64];    // Y tile, XOR-swizzled
  __shared__ __align__(16) unsigned short hs[64 * 128];   // h tile, XOR-swizzled
  float* f = ws;
  unsigned short* H = (unsigned short*)(ws + WS_H);
  const unsigned short* wlT = (const unsigned short*)(ws + WS_WLT);
  const unsigned short* Abf = XT + A_U16;
  const int t = threadIdx.x;
  const int wv = t >> 6, lane = t & 63;
  const int m = lane & 15, quad = lane >> 4;
  const int b = blockIdx.x >> 3, ns = blockIdx.x & 7;
  const int n0 = ns * 64;

  // ---- Y GEMM: Y^T[f][n] = XT_b[f][:] . A[n][:] ----
  const unsigned short* af = XT + (size_t)b * (F_ * N_) + (wv * 16 + m) * N_;
  f32x4 acc[4] = {{0.f,0.f,0.f,0.f},{0.f,0.f,0.f,0.f},
                  {0.f,0.f,0.f,0.f},{0.f,0.f,0.f,0.f}};
  #pragma unroll 4
  for (int kk = 0; kk < 16; kk++) {
    const int k0 = kk * 32 + quad * 8;
    bf16x8 a = *(const bf16x8*)(af + k0);
    #pragma unroll
    for (int nt = 0; nt < 4; nt++) {
      bf16x8 bb = *(const bf16x8*)(Abf + (n0 + nt * 16 + m) * N_ + k0);
      acc[nt] = __builtin_amdgcn_mfma_f32_16x16x32_bf16(a, bb, acc[nt], 0, 0, 0);
    }
  }
  // store Y tile to LDS: ys[n][f ^ ((n&7)<<3)], 8B-block-preserving swizzle
  #pragma unroll
  for (int nt = 0; nt < 4; nt++) {
    const int n = nt * 16 + m;
    const int c = (wv * 16 + quad * 4) ^ ((n & 7) << 3);
    ushort4 y4;
    y4.x = f2b(acc[nt][0]); y4.y = f2b(acc[nt][1]);
    y4.z = f2b(acc[nt][2]); y4.w = f2b(acc[nt][3]);
    *(ushort4*)(ys + n * 64 + c) = y4;
  }
  __syncthreads();

  // ---- h GEMM: h[n][d] = sum_f Y[n][f] Wl[f][d]; wave wv owns d0=wv*32 ----
  const int d0 = wv * 32;
  bf16x8 bw00 = *(const bf16x8*)(wlT + (d0 + m) * 64 + quad * 8);
  bf16x8 bw01 = *(const bf16x8*)(wlT + (d0 + m) * 64 + 32 + quad * 8);
  bf16x8 bw10 = *(const bf16x8*)(wlT + (d0 + 16 + m) * 64 + quad * 8);
  bf16x8 bw11 = *(const bf16x8*)(wlT + (d0 + 16 + m) * 64 + 32 + quad * 8);
  f32x4 acch[4][2];
  #pragma unroll
  for (int nt = 0; nt < 4; nt++) {
    acch[nt][0] = f32x4{0.f,0.f,0.f,0.f};
    acch[nt][1] = f32x4{0.f,0.f,0.f,0.f};
  }
  #pragma unroll
  for (int nt = 0; nt < 4; nt++) {
    const int n2 = nt * 16 + m;
    const int sw = (n2 & 7) << 3;
    bf16x8 aA = *(const bf16x8*)(ys + n2 * 64 + ((quad * 8) ^ sw));
    bf16x8 aB = *(const bf16x8*)(ys + n2 * 64 + ((32 + quad * 8) ^ sw));
    acch[nt][0] = __builtin_amdgcn_mfma_f32_16x16x32_bf16(aA, bw00, acch[nt][0], 0, 0, 0);
    acch[nt][0] = __builtin_amdgcn_mfma_f32_16x16x32_bf16(aB, bw01, acch[nt][0], 0, 0, 0);
    acch[nt][1] = __builtin_amdgcn_mfma_f32_16x16x32_bf16(aA, bw10, acch[nt][1], 0, 0, 0);
    acch[nt][1] = __builtin_amdgcn_mfma_f32_16x16x32_bf16(aB, bw11, acch[nt][1], 0, 0, 0);
  }

  // ---- h-tile scatter into swizzled LDS + register stat accumulation ----
  float sm0 = 0.f, sq0 = 0.f, sm1 = 0.f, sq1 = 0.f;
  #pragma unroll
  for (int nt = 0; nt < 4; nt++) {
    #pragma unroll
    for (int i = 0; i < 4; i++) {
      const int n = nt * 16 + quad * 4 + i;
      const int swn = (n & 7) << 3;
      float v0 = acch[nt][0][i], v1 = acch[nt][1][i];
      sm0 += v0; sq0 += v0 * v0;
      sm1 += v1; sq1 += v1 * v1;
      hs[n * 128 + ((d0 + m) ^ swn)]      = f2b(v0);
      hs[n * 128 + ((d0 + 16 + m) ^ swn)] = f2b(v1);
    }
  }
  __syncthreads();

  // ---- coalesced H write (un-swizzle via 16B block reads) ----
  unsigned short* Hb = H + ((size_t)b * N_ + n0) * D_;
  #pragma unroll
  for (int k = 0; k < 4; k++) {
    const int cidx = k * 256 + t;                 // 1024 x 16B chunks
    const int n = cidx >> 4, cb = (cidx & 15) << 3;
    *(uint4*)(Hb + n * 128 + cb) =
        *(const uint4*)(hs + n * 128 + (cb ^ ((n & 7) << 3)));
  }

  // ---- stats: shuffle reduce + bucketed atomics (NO barrier after) ----
  sm0 += __shfl_xor(sm0, 16); sm0 += __shfl_xor(sm0, 32);
  sq0 += __shfl_xor(sq0, 16); sq0 += __shfl_xor(sq0, 32);
  sm1 += __shfl_xor(sm1, 16); sm1 += __shfl_xor(sm1, 32);
  sq1 += __shfl_xor(sq1, 16); sq1 += __shfl_xor(sq1, 32);
  if (quad == 0) {
    float* st = f + WS_STATS + (blockIdx.x & (NBKT - 1)) * 256;
    atomicAdd(&st[d0 + m], sm0);
    atomicAdd(&st[128 + d0 + m], sq0);
    atomicAdd(&st[d0 + 16 + m], sm1);
    atomicAdd(&st[128 + d0 + 16 + m], sq1);
  }
}

// K2: epilogue: read H, BN+ReLU (z = h*rs + zb), zs -> GEMM2 + pred head.
__global__ __launch_bounds__(256) void kD(
    const float* __restrict__ gamma, const float* __restrict__ beta,
    const float* __restrict__ br, const float* __restrict__ wp,
    const float* __restrict__ bp, float* ws, float* __restrict__ out)
{
  constexpr int LDP = 136;                        // zs row pad: breaks 256B stride
  __shared__ __align__(16) unsigned short zs[16 * LDP];
  __shared__ float rsL[D_], zbL[D_], wpL[D_];
  float* f = ws;
  const unsigned short* H   = (const unsigned short*)(f + WS_H);
  const unsigned short* wrT = (const unsigned short*)(f + WS_WRT);
  const int t = threadIdx.x;
  const int wv = t >> 6, lane = t & 63;
  const int m = lane & 15, quad = lane >> 4;
  const size_t row0 = (size_t)blockIdx.x * 16;

  if (t < 128) {
    float s = 0.f, sq = 0.f;
    #pragma unroll
    for (int bk = 0; bk < NBKT; bk++) {
      s  += f[WS_STATS + bk * 256 + t];
      sq += f[WS_STATS + bk * 256 + 128 + t];
    }
    float mu  = s * (1.f / (float)BN_);
    float var = sq * (1.f / (float)BN_) - mu * mu;
    float rg  = rsqrtf(var + EPS_) * gamma[t];
    rsL[t] = rg;
    zbL[t] = beta[t] - mu * rg;
    wpL[t] = wp[t];
  }
  __syncthreads();

  // ---- BN + ReLU: each thread handles 8 consecutive d of one row ----
  {
    const int r = t >> 4, c8 = (t & 15) << 3;
    bf16x8 h8 = *(const bf16x8*)(H + (row0 + r) * D_ + c8);
    ushort4 za, zb4;
    #pragma unroll
    for (int j = 0; j < 8; j++) {
      float z = fmaf(b2f((unsigned short)h8[j]), rsL[c8 + j], zbL[c8 + j]);
      z = z > 0.f ? z : 0.f;
      unsigned short zb16 = f2b(z);
      if (j < 4) ((unsigned short*)&za)[j] = zb16;
      else       ((unsigned short*)&zb4)[j - 4] = zb16;
    }
    *(ushort4*)(zs + r * LDP + c8)     = za;
    *(ushort4*)(zs + r * LDP + c8 + 4) = zb4;
  }
  __syncthreads();

  // ---- GEMM2: recons tile [16 x 64], wave wv -> col-tile wv ----
  {
    const int col = wv * 16 + m;
    float bias = br[col];
    f32x4 acc2 = {bias, bias, bias, bias};
    #pragma unroll
    for (int s = 0; s < 4; s++) {
      bf16x8 az = *(const bf16x8*)(zs + m * LDP + s * 32 + quad * 8);
      bf16x8 bz = *(const bf16x8*)(wrT + col * D_ + s * 32 + quad * 8);
      acc2 = __builtin_amdgcn_mfma_f32_16x16x32_bf16(az, bz, acc2, 0, 0, 0);
    }
    #pragma unroll
    for (int i = 0; i < 4; i++)
      out[(row0 + quad * 4 + i) * F_ + col] = acc2[i];
  }

  // ---- pred head: 8 lanes per row, 16 d each, shuffle reduce ----
  if (t < 128) {
    const int r = t >> 3, j = t & 7;
    float a = 0.f;
    #pragma unroll
    for (int k = 0; k < 16; k++) {
      const int d = j * 16 + k;
      a += b2f(zs[r * LDP + d]) * wpL[d];
    }
    a += __shfl_xor(a, 1); a += __shfl_xor(a, 2); a += __shfl_xor(a, 4);
    if (j == 0) out[OFF_PRED + row0 + r] = a + bp[0];
  }
}

extern "C" void kernel_launch(void* const* d_in, const int* in_sizes, int n_in,
                              void* d_out, int out_size, void* d_ws, size_t ws_size,
                              hipStream_t stream) {
  const float* data  = (const float*)d_in[0];
  const int*   ei    = (const int*)d_in[1];
  const float* W     = (const float*)d_in[2];
  const float* lin_w = (const float*)d_in[3];
  // d_in[4] = gnn_bias: cancels exactly through training-mode BN
  const float* gamma = (const float*)d_in[5];
  const float* beta  = (const float*)d_in[6];
  const float* Wr    = (const float*)d_in[7];
  const float* br    = (const float*)d_in[8];
  const float* wp    = (const float*)d_in[9];
  const float* bp    = (const float*)d_in[10];
  float* out = (float*)d_out;
  float* ws  = (float*)d_ws;
  unsigned short* outs = (unsigned short*)d_out;   // XT @0, A @A_U16 (scratch)

  k_prep <<<1088,      256, 0, stream>>>(data, W, lin_w, Wr, ei, ws, outs, out);
  kBC    <<<B_ * 8,    256, 0, stream>>>(outs, ws);
  kD     <<<BN_ / 16,  256, 0, stream>>>(gamma, beta, br, wp, bp, ws, out);
}